// Round 2
// baseline (248.559 us; speedup 1.0000x reference)
//
#include <hip/hip_runtime.h>
#include <hip/hip_cooperative_groups.h>

namespace cg = cooperative_groups;

// ---------- types ----------
typedef short short8 __attribute__((ext_vector_type(8)));        // 8 bf16 MFMA A/B frag
typedef float floatx4 __attribute__((ext_vector_type(4)));       // MFMA C/D frag

__device__ __forceinline__ unsigned short f2bf(float f) {
    unsigned u = __float_as_uint(f);
    u += 0x7fffu + ((u >> 16) & 1u);   // RNE
    return (unsigned short)(u >> 16);
}
__device__ __forceinline__ float bf2f(unsigned short b) {
    unsigned u = (unsigned)b << 16;
    return __uint_as_float(u);
}

#define MFMA16(a, b, c)  __builtin_amdgcn_mfma_f32_16x16x32_bf16((a), (b), (c), 0, 0, 0)

// ---------- ws layout (bytes) ----------
static constexpr size_t Q_OFF    = 0;                    // q*QSCALE packed bf16 2 MB
static constexpr size_t K_OFF    = 2u << 20;             // k packed bf16        2 MB
static constexpr size_t U_OFF    = 4u << 20;             // u fp32 [8192]       32 KB
static constexpr size_t WFCT_OFF = U_OFF + 32768;        // W_fc packed bf16   256 KB
static constexpr size_t WGT_OFF  = WFCT_OFF + 262144;    // W_gate packed bf16
static constexpr size_t WQT_OFF  = WGT_OFF + 262144;     // W_q packed bf16     32 KB
static constexpr size_t WKT_OFF  = WQT_OFF + 32768;      // W_k packed bf16
static constexpr size_t WVO_OFF  = WKT_OFF + 32768;      // wvo fp32 [128] + c0
static constexpr size_t PB_OFF   = 5u << 20;             // partials float2 [8192][16] 1 MB

static constexpr int NSPLIT = 16;
// log2(e)/sqrt(128): folded into stored q so P = exp2(S)
static constexpr float QSCALE = 0.1275174308f;

struct KParams {
    const float *x, *wfc, *bfc, *wg, *bg, *wq, *bq, *wk, *bk, *wv, *bv, *wout, *bout;
    float* out;
    unsigned short *wfcp, *wgp, *wqp, *wkp, *qpk, *kpk;
    float *wvo, *ug;
    float2* pb;
};

// =====================================================================
// R0/R1: single cooperative kernel — phases {prep, gq, flash, out} joined by
// grid.sync(). Eliminates 3 dispatch drains + L2 invalidations; makes our
// work visible as ONE rocprof dispatch with attributable counters.
// Inner loops of gq/flash are the harness-verified r12 structures verbatim.
// =====================================================================
__global__ __launch_bounds__(512, 2) void k_fused(KParams p) {
    __shared__ __align__(16) unsigned short xs[2][32 * 136];
    __shared__ __align__(16) float gbuf[32 * 132];
    __shared__ __align__(16) unsigned short hs[32 * 136];

    cg::grid_group grid = cg::this_grid();
    const int tid = threadIdx.x;

    // ---------------- phase 0: weight pack + wvo GEMV ----------------
    {
        const int g = blockIdx.x * 512 + tid;          // 131072 threads
        for (int i = g; i < 294912; i += 131072) {     // 2-3 elems/thread
            const float* s; unsigned short* d; int base, nchunk;
            if (i < 131072)      { s = p.wfc; d = p.wfcp; nchunk = 32; base = 0; }
            else if (i < 262144) { s = p.wg;  d = p.wgp;  nchunk = 32; base = 131072; }
            else if (i < 278528) { s = p.wq;  d = p.wqp;  nchunk = 4;  base = 262144; }
            else                 { s = p.wk;  d = p.wkp;  nchunk = 4;  base = 278528; }
            int j = i - base;
            int kk = j >> 7, nn = j & 127;             // source W[kk][nn]
            int t = nn >> 4, lr = nn & 15;
            int c = kk >> 5, lk = (kk >> 3) & 3, e = kk & 7;
            d[(((t * nchunk + c) * 64) + lr + 16 * lk) * 8 + e] = f2bf(s[j]);
        }
        // wvo = W_v @ W_out (parallel: 2 threads/output; was 128-iter serial chain)
        if (blockIdx.x == 255) {
            if (tid < 256) {
                int o = tid >> 1, hf = tid & 1;
                const float* wr = p.wv + o * 128 + hf * 64;
                const float* wo = p.wout + hf * 64;
                float s = 0.f;
#pragma unroll
                for (int j = 0; j < 64; ++j) s += wr[j] * wo[j];
                s += __shfl_xor(s, 1);
                if (hf == 0) p.wvo[o] = s;
            } else if (tid >= 384 && tid < 448) {      // c0 = bv @ W_out, one wave
                int l = tid - 384;
                float s = p.bv[l] * p.wout[l] + p.bv[l + 64] * p.wout[l + 64];
#pragma unroll
                for (int d2 = 1; d2 < 64; d2 <<= 1) s += __shfl_xor(s, d2);
                if (l == 0) p.wvo[128] = s;
            }
        }
    }
    grid.sync();

    // ---------------- phase 1: gated-linear + QK + u (k_gq verbatim) ----------------
    {
        const int i0 = blockIdx.x * 32;
        const int w = tid >> 6, lane = tid & 63;
        const int lr = lane & 15, lk = lane >> 4;

        const int isg = (w >= 4);
        const int wq4 = w & 3;
        const unsigned short* wp = isg ? p.wgp : p.wfcp;

        floatx4 acc[2][2];
#pragma unroll
        for (int mt = 0; mt < 2; ++mt)
#pragma unroll
            for (int nt = 0; nt < 2; ++nt) acc[mt][nt] = (floatx4)0.0f;

        const int srow = tid >> 4, se = tid & 15;
        const float* gp0 = p.x + (size_t)(i0 + srow) * 1024 + se * 8;
        float4 ra = *(const float4*)gp0;
        float4 rb = *(const float4*)(gp0 + 4);

        for (int kc = 0; kc < 8; ++kc) {
            {   // commit prefetched chunk to LDS buf kc&1 (fp32 -> bf16)
                short8 t;
                unsigned short* tp = (unsigned short*)&t;
                tp[0] = f2bf(ra.x); tp[1] = f2bf(ra.y); tp[2] = f2bf(ra.z); tp[3] = f2bf(ra.w);
                tp[4] = f2bf(rb.x); tp[5] = f2bf(rb.y); tp[6] = f2bf(rb.z); tp[7] = f2bf(rb.w);
                *(short8*)(xs[kc & 1] + srow * 136 + se * 8) = t;
            }
            if (kc < 7) {
                const float* gp = gp0 + (kc + 1) * 128;
                ra = *(const float4*)gp;
                rb = *(const float4*)(gp + 4);
            }
            __syncthreads();
            const unsigned short* xb = xs[kc & 1];
#pragma unroll
            for (int ks = 0; ks < 4; ++ks) {
                const int c = kc * 4 + ks;
                short8 a[2], b[2];
#pragma unroll
                for (int mt = 0; mt < 2; ++mt)
                    a[mt] = *(const short8*)(xb + (mt * 16 + lr) * 136 + ks * 32 + lk * 8);
#pragma unroll
                for (int nt = 0; nt < 2; ++nt)
                    b[nt] = *(const short8*)(wp + ((((size_t)(wq4 * 2 + nt)) * 32 + c) * 64 + lane) * 8);
#pragma unroll
                for (int mt = 0; mt < 2; ++mt)
#pragma unroll
                    for (int nt = 0; nt < 2; ++nt)
                        acc[mt][nt] = MFMA16(a[mt], b[nt], acc[mt][nt]);
            }
        }
        __syncthreads();
        if (isg) {
#pragma unroll
            for (int mt = 0; mt < 2; ++mt)
#pragma unroll
                for (int nt = 0; nt < 2; ++nt) {
                    int col = wq4 * 32 + nt * 16 + lr;
                    float bb = p.bg[col];
#pragma unroll
                    for (int r = 0; r < 4; ++r) {
                        float v = acc[mt][nt][r] + bb;
                        gbuf[(mt * 16 + lk * 4 + r) * 132 + col] =
                            __builtin_amdgcn_rcpf(1.0f + __builtin_amdgcn_exp2f(-1.4426950408889634f * v));
                    }
                }
        }
        __syncthreads();
        if (!isg) {
#pragma unroll
            for (int mt = 0; mt < 2; ++mt)
#pragma unroll
                for (int nt = 0; nt < 2; ++nt) {
                    int col = wq4 * 32 + nt * 16 + lr;
                    float bb = p.bfc[col];
#pragma unroll
                    for (int r = 0; r < 4; ++r) {
                        int row = mt * 16 + lk * 4 + r;
                        hs[row * 136 + col] = f2bf((acc[mt][nt][r] + bb) * gbuf[row * 132 + col]);
                    }
                }
        }
        __syncthreads();

        // u[i] = h[i] @ wvo + c0
        {
            int row = tid >> 4, c = tid & 15;
            float s = 0.f;
#pragma unroll
            for (int e = 0; e < 8; ++e)
                s += bf2f(hs[row * 136 + c * 8 + e]) * p.wvo[c * 8 + e];
#pragma unroll
            for (int d = 1; d < 16; d <<= 1) s += __shfl_xor(s, d);
            if (c == 0) p.ug[i0 + row] = s + p.wvo[128];
        }

        // Phase B: q (w<4) | k (w>=4)
        floatx4 qacc[2][2];
#pragma unroll
        for (int mt = 0; mt < 2; ++mt)
#pragma unroll
            for (int nt = 0; nt < 2; ++nt) qacc[mt][nt] = (floatx4)0.0f;
        const unsigned short* wbp = (w < 4) ? p.wqp : p.wkp;
#pragma unroll
        for (int ks = 0; ks < 4; ++ks) {
            short8 a[2], b[2];
#pragma unroll
            for (int mt = 0; mt < 2; ++mt)
                a[mt] = *(const short8*)(hs + (mt * 16 + lr) * 136 + ks * 32 + lk * 8);
#pragma unroll
            for (int nt = 0; nt < 2; ++nt)
                b[nt] = *(const short8*)(wbp + ((((size_t)(wq4 * 2 + nt)) * 4 + ks) * 64 + lane) * 8);
#pragma unroll
            for (int mt = 0; mt < 2; ++mt)
#pragma unroll
                for (int nt = 0; nt < 2; ++nt)
                    qacc[mt][nt] = MFMA16(a[mt], b[nt], qacc[mt][nt]);
        }
        {
            unsigned short* dstl = xs[isg];
            const float* bb_ = (w < 4) ? p.bq : p.bk;
            const float sc = (w < 4) ? QSCALE : 1.0f;
#pragma unroll
            for (int mt = 0; mt < 2; ++mt)
#pragma unroll
                for (int nt = 0; nt < 2; ++nt) {
                    int col = wq4 * 32 + nt * 16 + lr;
                    float bb = bb_[col];
#pragma unroll
                    for (int r = 0; r < 4; ++r)
                        dstl[(mt * 16 + lk * 4 + r) * 136 + col] = f2bf((qacc[mt][nt][r] + bb) * sc);
                }
        }
        __syncthreads();
        {   // cooperative packed store
            int sel = w >> 2, pp = w & 3;
            int rtl = pp >> 1, ks2 = (pp & 1) * 2;
            unsigned short* gdst = sel ? p.kpk : p.qpk;
            const unsigned short* src = xs[sel];
            size_t rt = (i0 >> 4) + rtl;
#pragma unroll
            for (int s = 0; s < 2; ++s) {
                int ks = ks2 + s;
                short8 v = *(const short8*)(src + (rtl * 16 + lr) * 136 + ks * 32 + lk * 8);
                *(short8*)(gdst + ((rt * 4 + ks) * 64 + lane) * 8) = v;
            }
        }
    }
    grid.sync();

    // ---------------- phase 2: flash (k_flash verbatim; wave w8 -> flash-block 2b+(w8>>2)) ----------------
    {
        const int w8 = tid >> 6, lane = tid & 63;
        const int f = blockIdx.x * 2 + (w8 >> 2);   // 0..511 flash-block id
        const int bx = f & 31, by = f >> 5;         // bx: q rows, by: split
        const int w = w8 & 3;
        const int lr = lane & 15, lk = lane >> 4;
        const int rt0 = bx * 16 + w * 4;

        short8 qf[4][4];
#pragma unroll
        for (int mt = 0; mt < 4; ++mt)
#pragma unroll
            for (int ks = 0; ks < 4; ++ks)
                qf[mt][ks] = *(const short8*)(p.qpk + (((size_t)(rt0 + mt) * 4 + ks) * 64 + lane) * 8);

        float numv[4] = {0.f, 0.f, 0.f, 0.f};
        float lsum[4] = {0.f, 0.f, 0.f, 0.f};

        const int jt0 = by * 32;

        short8 af[4], afn[4];
        floatx4 uu, uun;
#pragma unroll
        for (int ks = 0; ks < 4; ++ks)
            af[ks] = *(const short8*)(p.kpk + (((size_t)jt0 * 4 + ks) * 64 + lane) * 8);
        uu = *(const floatx4*)(p.ug + jt0 * 16 + lk * 4);

        for (int t = 0; t < 32; ++t) {
            if (t < 31) {
#pragma unroll
                for (int ks = 0; ks < 4; ++ks)
                    afn[ks] = *(const short8*)(p.kpk + (((size_t)(jt0 + t + 1) * 4 + ks) * 64 + lane) * 8);
                uun = *(const floatx4*)(p.ug + (jt0 + t + 1) * 16 + lk * 4);
            }
            floatx4 sacc[4];
#pragma unroll
            for (int mt = 0; mt < 4; ++mt) sacc[mt] = (floatx4)0.0f;
#pragma unroll
            for (int ks = 0; ks < 4; ++ks)
#pragma unroll
                for (int mt = 0; mt < 4; ++mt)
                    sacc[mt] = MFMA16(af[ks], qf[mt][ks], sacc[mt]);
#pragma unroll
            for (int mt = 0; mt < 4; ++mt) {
#pragma unroll
                for (int r = 0; r < 4; ++r) {
                    float pv = __builtin_amdgcn_exp2f(sacc[mt][r]);
                    numv[mt] += pv * uu[r];
                    lsum[mt] += pv;
                }
            }
#pragma unroll
            for (int ks = 0; ks < 4; ++ks) af[ks] = afn[ks];
            uu = uun;
        }

#pragma unroll
        for (int mt = 0; mt < 4; ++mt) {
            float n = numv[mt], l = lsum[mt];
            n += __shfl_xor(n, 16); n += __shfl_xor(n, 32);
            l += __shfl_xor(l, 16); l += __shfl_xor(l, 32);
            if (lk == 0) {
                size_t row = (size_t)(rt0 + mt) * 16 + lr;
                p.pb[row * NSPLIT + by] = make_float2(n, l);
            }
        }
    }
    grid.sync();

    // ---------------- phase 3: out ----------------
    {
        int row = blockIdx.x * 512 + tid;
        if (row < 8192) {
            const float2* pr = p.pb + (size_t)row * NSPLIT;
            float n = 0.f, l = 0.f;
#pragma unroll
            for (int s = 0; s < NSPLIT; ++s) {
                float2 v = pr[s];
                n += v.x; l += v.y;
            }
            p.out[row] = n / l + p.bout[0];
        }
    }
}

// =====================================================================
// Fallback path: the harness-verified 4-kernel pipeline (used only if
// cooperative launch is rejected, e.g. under graph capture).
// =====================================================================
__global__ void k_prep(const float* __restrict__ wfc, const float* __restrict__ wg,
                       const float* __restrict__ wq, const float* __restrict__ wk,
                       const float* __restrict__ wv, const float* __restrict__ wout,
                       const float* __restrict__ bv,
                       unsigned short* __restrict__ dfc, unsigned short* __restrict__ dg,
                       unsigned short* __restrict__ dq, unsigned short* __restrict__ dk,
                       float* __restrict__ wvo) {
    if (blockIdx.x == 1216) {
        int t = threadIdx.x;
        if (t < 128) {
            float s = 0.f;
            for (int j = 0; j < 128; ++j) s += wv[t * 128 + j] * wout[j];
            wvo[t] = s;
        } else if (t == 128) {
            float s = 0.f;
            for (int j = 0; j < 128; ++j) s += bv[j] * wout[j];
            wvo[128] = s;
        }
        return;
    }
    int i = blockIdx.x * 256 + threadIdx.x;
    const float* s; unsigned short* d; int base, nchunk;
    if (i < 131072)      { s = wfc; d = dfc; nchunk = 32; base = 0; }
    else if (i < 262144) { s = wg;  d = dg;  nchunk = 32; base = 131072; }
    else if (i < 278528) { s = wq;  d = dq;  nchunk = 4;  base = 262144; }
    else if (i < 294912) { s = wk;  d = dk;  nchunk = 4;  base = 278528; }
    else return;
    int j = i - base;
    int kk = j >> 7, nn = j & 127;
    int t = nn >> 4, lr = nn & 15;
    int c = kk >> 5, lk = (kk >> 3) & 3, e = kk & 7;
    d[(((t * nchunk + c) * 64) + lr + 16 * lk) * 8 + e] = f2bf(s[j]);
}

__global__ __launch_bounds__(512) void k_gq(const float* __restrict__ x,
                                            const unsigned short* __restrict__ wfcp,
                                            const unsigned short* __restrict__ wgp,
                                            const float* __restrict__ bfc,
                                            const float* __restrict__ bg,
                                            const unsigned short* __restrict__ wqp,
                                            const unsigned short* __restrict__ wkp,
                                            const float* __restrict__ bq,
                                            const float* __restrict__ bk,
                                            const float* __restrict__ wvo,
                                            unsigned short* __restrict__ qpk,
                                            unsigned short* __restrict__ kpk,
                                            float* __restrict__ ug) {
    __shared__ __align__(16) unsigned short xs[2][32 * 136];
    __shared__ __align__(16) float gbuf[32 * 132];
    __shared__ __align__(16) unsigned short hs[32 * 136];
    const int tid = threadIdx.x;
    const int i0 = blockIdx.x * 32;
    const int w = tid >> 6, lane = tid & 63;
    const int lr = lane & 15, lk = lane >> 4;
    const int isg = (w >= 4);
    const int wq4 = w & 3;
    const unsigned short* wp = isg ? wgp : wfcp;
    floatx4 acc[2][2];
#pragma unroll
    for (int mt = 0; mt < 2; ++mt)
#pragma unroll
        for (int nt = 0; nt < 2; ++nt) acc[mt][nt] = (floatx4)0.0f;
    const int srow = tid >> 4, se = tid & 15;
    const float* gp0 = x + (size_t)(i0 + srow) * 1024 + se * 8;
    float4 ra = *(const float4*)gp0;
    float4 rb = *(const float4*)(gp0 + 4);
    for (int kc = 0; kc < 8; ++kc) {
        {
            short8 t;
            unsigned short* tp = (unsigned short*)&t;
            tp[0] = f2bf(ra.x); tp[1] = f2bf(ra.y); tp[2] = f2bf(ra.z); tp[3] = f2bf(ra.w);
            tp[4] = f2bf(rb.x); tp[5] = f2bf(rb.y); tp[6] = f2bf(rb.z); tp[7] = f2bf(rb.w);
            *(short8*)(xs[kc & 1] + srow * 136 + se * 8) = t;
        }
        if (kc < 7) {
            const float* gp = gp0 + (kc + 1) * 128;
            ra = *(const float4*)gp;
            rb = *(const float4*)(gp + 4);
        }
        __syncthreads();
        const unsigned short* xb = xs[kc & 1];
#pragma unroll
        for (int ks = 0; ks < 4; ++ks) {
            const int c = kc * 4 + ks;
            short8 a[2], b[2];
#pragma unroll
            for (int mt = 0; mt < 2; ++mt)
                a[mt] = *(const short8*)(xb + (mt * 16 + lr) * 136 + ks * 32 + lk * 8);
#pragma unroll
            for (int nt = 0; nt < 2; ++nt)
                b[nt] = *(const short8*)(wp + ((((size_t)(wq4 * 2 + nt)) * 32 + c) * 64 + lane) * 8);
#pragma unroll
            for (int mt = 0; mt < 2; ++mt)
#pragma unroll
                for (int nt = 0; nt < 2; ++nt)
                    acc[mt][nt] = MFMA16(a[mt], b[nt], acc[mt][nt]);
        }
    }
    __syncthreads();
    if (isg) {
#pragma unroll
        for (int mt = 0; mt < 2; ++mt)
#pragma unroll
            for (int nt = 0; nt < 2; ++nt) {
                int col = wq4 * 32 + nt * 16 + lr;
                float bb = bg[col];
#pragma unroll
                for (int r = 0; r < 4; ++r) {
                    float v = acc[mt][nt][r] + bb;
                    gbuf[(mt * 16 + lk * 4 + r) * 132 + col] =
                        __builtin_amdgcn_rcpf(1.0f + __builtin_amdgcn_exp2f(-1.4426950408889634f * v));
                }
            }
    }
    __syncthreads();
    if (!isg) {
#pragma unroll
        for (int mt = 0; mt < 2; ++mt)
#pragma unroll
            for (int nt = 0; nt < 2; ++nt) {
                int col = wq4 * 32 + nt * 16 + lr;
                float bb = bfc[col];
#pragma unroll
                for (int r = 0; r < 4; ++r) {
                    int row = mt * 16 + lk * 4 + r;
                    hs[row * 136 + col] = f2bf((acc[mt][nt][r] + bb) * gbuf[row * 132 + col]);
                }
            }
    }
    __syncthreads();
    {
        int row = tid >> 4, c = tid & 15;
        float s = 0.f;
#pragma unroll
        for (int e = 0; e < 8; ++e)
            s += bf2f(hs[row * 136 + c * 8 + e]) * wvo[c * 8 + e];
#pragma unroll
        for (int d = 1; d < 16; d <<= 1) s += __shfl_xor(s, d);
        if (c == 0) ug[i0 + row] = s + wvo[128];
    }
    floatx4 qacc[2][2];
#pragma unroll
    for (int mt = 0; mt < 2; ++mt)
#pragma unroll
        for (int nt = 0; nt < 2; ++nt) qacc[mt][nt] = (floatx4)0.0f;
    const unsigned short* wbp = (w < 4) ? wqp : wkp;
#pragma unroll
    for (int ks = 0; ks < 4; ++ks) {
        short8 a[2], b[2];
#pragma unroll
        for (int mt = 0; mt < 2; ++mt)
            a[mt] = *(const short8*)(hs + (mt * 16 + lr) * 136 + ks * 32 + lk * 8);
#pragma unroll
        for (int nt = 0; nt < 2; ++nt)
            b[nt] = *(const short8*)(wbp + ((((size_t)(wq4 * 2 + nt)) * 4 + ks) * 64 + lane) * 8);
#pragma unroll
        for (int mt = 0; mt < 2; ++mt)
#pragma unroll
            for (int nt = 0; nt < 2; ++nt)
                qacc[mt][nt] = MFMA16(a[mt], b[nt], qacc[mt][nt]);
    }
    {
        unsigned short* dstl = xs[isg];
        const float* bb_ = (w < 4) ? bq : bk;
        const float sc = (w < 4) ? QSCALE : 1.0f;
#pragma unroll
        for (int mt = 0; mt < 2; ++mt)
#pragma unroll
            for (int nt = 0; nt < 2; ++nt) {
                int col = wq4 * 32 + nt * 16 + lr;
                float bb = bb_[col];
#pragma unroll
                for (int r = 0; r < 4; ++r)
                    dstl[(mt * 16 + lk * 4 + r) * 136 + col] = f2bf((qacc[mt][nt][r] + bb) * sc);
            }
    }
    __syncthreads();
    {
        int sel = w >> 2, pp = w & 3;
        int rtl = pp >> 1, ks2 = (pp & 1) * 2;
        unsigned short* gdst = sel ? kpk : qpk;
        const unsigned short* src = xs[sel];
        size_t rt = (i0 >> 4) + rtl;
#pragma unroll
        for (int s = 0; s < 2; ++s) {
            int ks = ks2 + s;
            short8 v = *(const short8*)(src + (rtl * 16 + lr) * 136 + ks * 32 + lk * 8);
            *(short8*)(gdst + ((rt * 4 + ks) * 64 + lane) * 8) = v;
        }
    }
}

__global__ __launch_bounds__(256, 1) void k_flash(const unsigned short* __restrict__ qp,
                                                  const unsigned short* __restrict__ kp,
                                                  const float* __restrict__ ug,
                                                  float2* __restrict__ pb) {
    const int tid = threadIdx.x;
    const int w = tid >> 6, lane = tid & 63;
    const int lr = lane & 15, lk = lane >> 4;
    const int rt0 = blockIdx.x * 16 + w * 4;
    short8 qf[4][4];
#pragma unroll
    for (int mt = 0; mt < 4; ++mt)
#pragma unroll
        for (int ks = 0; ks < 4; ++ks)
            qf[mt][ks] = *(const short8*)(qp + (((size_t)(rt0 + mt) * 4 + ks) * 64 + lane) * 8);
    float numv[4] = {0.f, 0.f, 0.f, 0.f};
    float lsum[4] = {0.f, 0.f, 0.f, 0.f};
    const int jt0 = blockIdx.y * 32;
    short8 af[4], afn[4];
    floatx4 uu, uun;
#pragma unroll
    for (int ks = 0; ks < 4; ++ks)
        af[ks] = *(const short8*)(kp + (((size_t)jt0 * 4 + ks) * 64 + lane) * 8);
    uu = *(const floatx4*)(ug + jt0 * 16 + lk * 4);
    for (int t = 0; t < 32; ++t) {
        if (t < 31) {
#pragma unroll
            for (int ks = 0; ks < 4; ++ks)
                afn[ks] = *(const short8*)(kp + (((size_t)(jt0 + t + 1) * 4 + ks) * 64 + lane) * 8);
            uun = *(const floatx4*)(ug + (jt0 + t + 1) * 16 + lk * 4);
        }
        floatx4 sacc[4];
#pragma unroll
        for (int mt = 0; mt < 4; ++mt) sacc[mt] = (floatx4)0.0f;
#pragma unroll
        for (int ks = 0; ks < 4; ++ks)
#pragma unroll
            for (int mt = 0; mt < 4; ++mt)
                sacc[mt] = MFMA16(af[ks], qf[mt][ks], sacc[mt]);
#pragma unroll
        for (int mt = 0; mt < 4; ++mt) {
#pragma unroll
            for (int r = 0; r < 4; ++r) {
                float p = __builtin_amdgcn_exp2f(sacc[mt][r]);
                numv[mt] += p * uu[r];
                lsum[mt] += p;
            }
        }
#pragma unroll
        for (int ks = 0; ks < 4; ++ks) af[ks] = afn[ks];
        uu = uun;
    }
#pragma unroll
    for (int mt = 0; mt < 4; ++mt) {
        float n = numv[mt], l = lsum[mt];
        n += __shfl_xor(n, 16); n += __shfl_xor(n, 32);
        l += __shfl_xor(l, 16); l += __shfl_xor(l, 32);
        if (lk == 0) {
            size_t row = (size_t)(rt0 + mt) * 16 + lr;
            pb[row * NSPLIT + blockIdx.y] = make_float2(n, l);
        }
    }
}

__global__ __launch_bounds__(256) void k_out(const float2* __restrict__ pb,
                                             const float* __restrict__ bout,
                                             float* __restrict__ out) {
    int row = blockIdx.x * 256 + threadIdx.x;
    const float2* p = pb + (size_t)row * NSPLIT;
    float n = 0.f, l = 0.f;
#pragma unroll
    for (int s = 0; s < NSPLIT; ++s) {
        float2 v = p[s];
        n += v.x; l += v.y;
    }
    out[row] = n / l + bout[0];
}

// ---------- launch ----------
extern "C" void kernel_launch(void* const* d_in, const int* in_sizes, int n_in,
                              void* d_out, int out_size, void* d_ws, size_t ws_size,
                              hipStream_t stream) {
    const float* x    = (const float*)d_in[0];
    const float* Wfc  = (const float*)d_in[1];
    const float* bfc  = (const float*)d_in[2];
    const float* Wg   = (const float*)d_in[3];
    const float* bg   = (const float*)d_in[4];
    const float* Wq   = (const float*)d_in[5];
    const float* bq   = (const float*)d_in[6];
    const float* Wk   = (const float*)d_in[7];
    const float* bk   = (const float*)d_in[8];
    const float* Wv   = (const float*)d_in[9];
    const float* bv   = (const float*)d_in[10];
    const float* Wout = (const float*)d_in[11];
    const float* bout = (const float*)d_in[12];
    char* ws = (char*)d_ws;

    unsigned short* qb   = (unsigned short*)(ws + Q_OFF);
    unsigned short* kb   = (unsigned short*)(ws + K_OFF);
    float*          ub   = (float*)(ws + U_OFF);
    unsigned short* wfcp = (unsigned short*)(ws + WFCT_OFF);
    unsigned short* wgp  = (unsigned short*)(ws + WGT_OFF);
    unsigned short* wqp  = (unsigned short*)(ws + WQT_OFF);
    unsigned short* wkp  = (unsigned short*)(ws + WKT_OFF);
    float*          wvo  = (float*)(ws + WVO_OFF);
    float2*         pbb  = (float2*)(ws + PB_OFF);

    KParams prm;
    prm.x = x;     prm.wfc = Wfc;   prm.bfc = bfc; prm.wg = Wg;  prm.bg = bg;
    prm.wq = Wq;   prm.bq = bq;     prm.wk = Wk;   prm.bk = bk;  prm.wv = Wv;
    prm.bv = bv;   prm.wout = Wout; prm.bout = bout;
    prm.out = (float*)d_out;
    prm.wfcp = wfcp; prm.wgp = wgp; prm.wqp = wqp; prm.wkp = wkp;
    prm.qpk = qb;  prm.kpk = kb;  prm.wvo = wvo; prm.ug = ub; prm.pb = pbb;

    void* args[] = { (void*)&prm };
    hipError_t err = hipLaunchCooperativeKernel((const void*)k_fused, dim3(256), dim3(512),
                                                args, 0u, stream);
    if (err != hipSuccess) {
        // fallback: harness-verified 4-kernel pipeline
        k_prep<<<1217, 256, 0, stream>>>(Wfc, Wg, Wq, Wk, Wv, Wout, bv, wfcp, wgp, wqp, wkp, wvo);
        k_gq<<<256, 512, 0, stream>>>(x, wfcp, wgp, bfc, bg, wqp, wkp, bq, bk, wvo, qb, kb, ub);
        dim3 gf(32, NSPLIT);
        k_flash<<<gf, 256, 0, stream>>>(qb, kb, ub, pbb);
        k_out<<<32, 256, 0, stream>>>(pbb, bout, (float*)d_out);
    }
}

// Round 4
// 138.181 us; speedup vs baseline: 1.7988x; 1.7988x over previous
//
#include <hip/hip_runtime.h>

// ---------- types ----------
typedef short short8 __attribute__((ext_vector_type(8)));        // 8 bf16 MFMA A/B frag
typedef float floatx4 __attribute__((ext_vector_type(4)));       // MFMA C/D frag

__device__ __forceinline__ unsigned short f2bf(float f) {
    unsigned u = __float_as_uint(f);
    u += 0x7fffu + ((u >> 16) & 1u);   // RNE
    return (unsigned short)(u >> 16);
}
__device__ __forceinline__ float bf2f(unsigned short b) {
    unsigned u = (unsigned)b << 16;
    return __uint_as_float(u);
}

#define MFMA16(a, b, c)  __builtin_amdgcn_mfma_f32_16x16x32_bf16((a), (b), (c), 0, 0, 0)

// ---------- ws layout (bytes) ----------
// q/k PACKED in MFMA-fragment order: element (row, d) at
//   ((rowtile*4 + ks)*64 + lane)*8 + e ; one wave frag = one coalesced 1 KB txn.
static constexpr size_t Q_OFF    = 0;                    // q*QSCALE packed bf16 2 MB
static constexpr size_t K_OFF    = 2u << 20;             // k packed bf16        2 MB
static constexpr size_t U_OFF    = 4u << 20;             // u fp32 [8192]       32 KB
static constexpr size_t WFCT_OFF = U_OFF + 32768;        // W_fc packed bf16   256 KB
static constexpr size_t WGT_OFF  = WFCT_OFF + 262144;    // W_gate packed bf16
static constexpr size_t WQT_OFF  = WGT_OFF + 262144;     // W_q packed bf16     32 KB
static constexpr size_t WKT_OFF  = WQT_OFF + 32768;      // W_k packed bf16
static constexpr size_t WVO_OFF  = WKT_OFF + 32768;      // wvo fp32 [128] + c0
static constexpr size_t PB_OFF   = 5u << 20;             // partials float2 [8192][16] 1 MB

static constexpr int NSPLIT = 16;
// log2(e)/sqrt(128): folded into stored q so P = exp2(S)
static constexpr float QSCALE = 0.1275174308f;

// ---------- K1: weights -> MFMA-packed bf16 + wvo = W_v @ W_out GEMV ----------
// R3: GEMV parallelized (2 thr/output, 64-elem dots) — old serial 128-iter
// dependent-load chain was a ~15us straggler (latency-bound, all pipes idle).
__global__ void k_prep(const float* __restrict__ wfc, const float* __restrict__ wg,
                       const float* __restrict__ wq, const float* __restrict__ wk,
                       const float* __restrict__ wv, const float* __restrict__ wout,
                       const float* __restrict__ bv,
                       unsigned short* __restrict__ dfc, unsigned short* __restrict__ dg,
                       unsigned short* __restrict__ dq, unsigned short* __restrict__ dk,
                       float* __restrict__ wvo) {
    if (blockIdx.x == 1216) {
        int t = threadIdx.x;
        {   // wvo[o] = dot(W_v[o,:], W_out): 2 threads per output
            int o = t >> 1, hf = t & 1;
            const float* wr = wv + o * 128 + hf * 64;
            const float* wo = wout + hf * 64;
            float s = 0.f;
#pragma unroll
            for (int j = 0; j < 64; ++j) s += wr[j] * wo[j];
            s += __shfl_xor(s, 1);
            if (hf == 0) wvo[o] = s;
        }
        if (t < 64) {   // c0 = bv @ W_out, one wave
            float s = bv[t] * wout[t] + bv[t + 64] * wout[t + 64];
#pragma unroll
            for (int d2 = 1; d2 < 64; d2 <<= 1) s += __shfl_xor(s, d2);
            if (t == 0) wvo[128] = s;
        }
        return;
    }
    int i = blockIdx.x * 256 + threadIdx.x;
    const float* s; unsigned short* d; int base, nchunk;
    if (i < 131072)      { s = wfc; d = dfc; nchunk = 32; base = 0; }
    else if (i < 262144) { s = wg;  d = dg;  nchunk = 32; base = 131072; }
    else if (i < 278528) { s = wq;  d = dq;  nchunk = 4;  base = 262144; }
    else if (i < 294912) { s = wk;  d = dk;  nchunk = 4;  base = 278528; }
    else return;
    int j = i - base;
    int kk = j >> 7, nn = j & 127;        // source W[kk][nn], row-major K x 128
    int t = nn >> 4, lr = nn & 15;
    int c = kk >> 5, lk = (kk >> 3) & 3, e = kk & 7;
    d[(((t * nchunk + c) * 64) + lr + 16 * lk) * 8 + e] = f2bf(s[j]);
}

// ---------- K2: fused gated-linear + QK + u (r12 structure, verbatim) ----------
__global__ __launch_bounds__(512) void k_gq(const float* __restrict__ x,
                                            const unsigned short* __restrict__ wfcp,
                                            const unsigned short* __restrict__ wgp,
                                            const float* __restrict__ bfc,
                                            const float* __restrict__ bg,
                                            const unsigned short* __restrict__ wqp,
                                            const unsigned short* __restrict__ wkp,
                                            const float* __restrict__ bq,
                                            const float* __restrict__ bk,
                                            const float* __restrict__ wvo,
                                            unsigned short* __restrict__ qpk,
                                            unsigned short* __restrict__ kpk,
                                            float* __restrict__ ug) {
    __shared__ __align__(16) unsigned short xs[2][32 * 136];
    __shared__ __align__(16) float gbuf[32 * 132];
    __shared__ __align__(16) unsigned short hs[32 * 136];
    const int tid = threadIdx.x;
    const int i0 = blockIdx.x * 32;
    const int w = tid >> 6, lane = tid & 63;
    const int lr = lane & 15, lk = lane >> 4;

    const int isg = (w >= 4);
    const int wq4 = w & 3;                 // 0..3: which 32-col group
    const unsigned short* wp = isg ? wgp : wfcp;

    floatx4 acc[2][2];
#pragma unroll
    for (int mt = 0; mt < 2; ++mt)
#pragma unroll
        for (int nt = 0; nt < 2; ++nt) acc[mt][nt] = (floatx4)0.0f;

    const int srow = tid >> 4, se = tid & 15;   // 32 rows x 16 thr, 8 floats each
    const float* gp0 = x + (size_t)(i0 + srow) * 1024 + se * 8;
    float4 ra = *(const float4*)gp0;
    float4 rb = *(const float4*)(gp0 + 4);

    for (int kc = 0; kc < 8; ++kc) {
        {   // commit prefetched chunk to LDS buf kc&1 (fp32 -> bf16)
            short8 t;
            unsigned short* tp = (unsigned short*)&t;
            tp[0] = f2bf(ra.x); tp[1] = f2bf(ra.y); tp[2] = f2bf(ra.z); tp[3] = f2bf(ra.w);
            tp[4] = f2bf(rb.x); tp[5] = f2bf(rb.y); tp[6] = f2bf(rb.z); tp[7] = f2bf(rb.w);
            *(short8*)(xs[kc & 1] + srow * 136 + se * 8) = t;
        }
        if (kc < 7) {
            const float* gp = gp0 + (kc + 1) * 128;
            ra = *(const float4*)gp;
            rb = *(const float4*)(gp + 4);
        }
        __syncthreads();
        const unsigned short* xb = xs[kc & 1];
#pragma unroll
        for (int ks = 0; ks < 4; ++ks) {
            const int c = kc * 4 + ks;
            short8 a[2], b[2];
#pragma unroll
            for (int mt = 0; mt < 2; ++mt)
                a[mt] = *(const short8*)(xb + (mt * 16 + lr) * 136 + ks * 32 + lk * 8);
#pragma unroll
            for (int nt = 0; nt < 2; ++nt)
                b[nt] = *(const short8*)(wp + ((((size_t)(wq4 * 2 + nt)) * 32 + c) * 64 + lane) * 8);
#pragma unroll
            for (int mt = 0; mt < 2; ++mt)
#pragma unroll
                for (int nt = 0; nt < 2; ++nt)
                    acc[mt][nt] = MFMA16(a[mt], b[nt], acc[mt][nt]);
        }
    }
    __syncthreads();
    // epilogue A: gate waves write sigmoid; fc waves combine -> h
    if (isg) {
#pragma unroll
        for (int mt = 0; mt < 2; ++mt)
#pragma unroll
            for (int nt = 0; nt < 2; ++nt) {
                int col = wq4 * 32 + nt * 16 + lr;
                float bb = bg[col];
#pragma unroll
                for (int r = 0; r < 4; ++r) {
                    float v = acc[mt][nt][r] + bb;
                    gbuf[(mt * 16 + lk * 4 + r) * 132 + col] =
                        __builtin_amdgcn_rcpf(1.0f + __builtin_amdgcn_exp2f(-1.4426950408889634f * v));
                }
            }
    }
    __syncthreads();
    if (!isg) {
#pragma unroll
        for (int mt = 0; mt < 2; ++mt)
#pragma unroll
            for (int nt = 0; nt < 2; ++nt) {
                int col = wq4 * 32 + nt * 16 + lr;
                float bb = bfc[col];
#pragma unroll
                for (int r = 0; r < 4; ++r) {
                    int row = mt * 16 + lk * 4 + r;
                    hs[row * 136 + col] = f2bf((acc[mt][nt][r] + bb) * gbuf[row * 132 + col]);
                }
            }
    }
    __syncthreads();

    // u[i] = h[i] @ wvo + c0 : thread t -> row t>>4, 8-elem chunk (t&15)*8
    {
        int row = tid >> 4, c = tid & 15;
        float s = 0.f;
#pragma unroll
        for (int e = 0; e < 8; ++e)
            s += bf2f(hs[row * 136 + c * 8 + e]) * wvo[c * 8 + e];
#pragma unroll
        for (int d = 1; d < 16; d <<= 1) s += __shfl_xor(s, d);
        if (c == 0) ug[i0 + row] = s + wvo[128];
    }

    // Phase B: q (w<4) | k (w>=4), 32 cols per wave, packed B
    floatx4 qacc[2][2];
#pragma unroll
    for (int mt = 0; mt < 2; ++mt)
#pragma unroll
        for (int nt = 0; nt < 2; ++nt) qacc[mt][nt] = (floatx4)0.0f;
    const unsigned short* wbp = (w < 4) ? wqp : wkp;
#pragma unroll
    for (int ks = 0; ks < 4; ++ks) {
        short8 a[2], b[2];
#pragma unroll
        for (int mt = 0; mt < 2; ++mt)
            a[mt] = *(const short8*)(hs + (mt * 16 + lr) * 136 + ks * 32 + lk * 8);
#pragma unroll
        for (int nt = 0; nt < 2; ++nt)
            b[nt] = *(const short8*)(wbp + ((((size_t)(wq4 * 2 + nt)) * 4 + ks) * 64 + lane) * 8);
#pragma unroll
        for (int mt = 0; mt < 2; ++mt)
#pragma unroll
            for (int nt = 0; nt < 2; ++nt)
                qacc[mt][nt] = MFMA16(a[mt], b[nt], qacc[mt][nt]);
    }
    // epilogue B: bias+scale -> LDS tile (xs reused: [0]=q, [1]=k)
    {
        unsigned short* dstl = xs[isg];
        const float* bb_ = (w < 4) ? bq : bk;
        const float sc = (w < 4) ? QSCALE : 1.0f;
#pragma unroll
        for (int mt = 0; mt < 2; ++mt)
#pragma unroll
            for (int nt = 0; nt < 2; ++nt) {
                int col = wq4 * 32 + nt * 16 + lr;
                float bb = bb_[col];
#pragma unroll
                for (int r = 0; r < 4; ++r)
                    dstl[(mt * 16 + lk * 4 + r) * 136 + col] = f2bf((qacc[mt][nt][r] + bb) * sc);
            }
    }
    __syncthreads();
    // cooperative packed store: 16 segments (sel,rtl,ks), wave w -> sel=w>>2, 2 ks each
    {
        int sel = w >> 2, p = w & 3;
        int rtl = p >> 1, ks2 = (p & 1) * 2;
        unsigned short* gdst = sel ? kpk : qpk;
        const unsigned short* src = xs[sel];
        size_t rt = (i0 >> 4) + rtl;
#pragma unroll
        for (int s = 0; s < 2; ++s) {
            int ks = ks2 + s;
            short8 v = *(const short8*)(src + (rtl * 16 + lr) * 136 + ks * 32 + lk * 8);
            *(short8*)(gdst + ((rt * 4 + ks) * 64 + lane) * 8) = v;
        }
    }
}

// ---------- K3: flash v9 — R3 restructure ----------
// Evidence (r2 fused counters): MfmaUtil 6.4 / VALUBusy 9.7 / Occ 22% ->
// latency-bound. Old flash: 2 waves/SIMD, 5 VMEM/iter/wave, every wave of a
// unit re-loading the SAME K frags from L2 (~256 MB L2 reads, 1-deep prefetch).
// Fix: (a) K-tile staged in LDS once per BLOCK (1 coalesced 16B load/thread,
// double-buffered, T14 issue-early/write-late, ONE barrier/iter) -> VMEM
// instrs /5, L2 traffic /4, latency hidden under full compute phase.
// (b) grid.x 32->64, 2 row-tiles/wave (qf[2][4], -32 VGPR) -> 1024 blocks,
// 3-4 blocks/CU resident vs 2 -> TLP 8 -> 12-16 waves/CU.
// Math identical to v8 (same MFMA, exp2, accumulation order) -> same absmax.
__global__ __launch_bounds__(256, 1) void k_flash(const unsigned short* __restrict__ qp,
                                                  const unsigned short* __restrict__ kp,
                                                  const float* __restrict__ ug,
                                                  float2* __restrict__ pb) {
    __shared__ __align__(16) unsigned short kls[2][256 * 8];   // 2 x 4 KB K-tile
    const int tid = threadIdx.x;
    const int w = tid >> 6, lane = tid & 63;
    const int lr = lane & 15, lk = lane >> 4;
    const int rt0 = blockIdx.x * 8 + w * 2;     // 64 x-blocks, 2 row-tiles/wave

    // Q frags: 8 coalesced 1KB loads, live in registers
    short8 qf[2][4];
#pragma unroll
    for (int mt = 0; mt < 2; ++mt)
#pragma unroll
        for (int ks = 0; ks < 4; ++ks)
            qf[mt][ks] = *(const short8*)(qp + (((size_t)(rt0 + mt) * 4 + ks) * 64 + lane) * 8);

    float numv[2] = {0.f, 0.f};
    float lsum[2] = {0.f, 0.f};

    const int jt0 = blockIdx.y * 32;            // 32 j row-tiles per split

    // prologue: stage tile jt0 into LDS buf 0 (one 16B load/thread, 4KB tile)
    *(short8*)(kls[0] + tid * 8) =
        *(const short8*)(kp + (size_t)jt0 * 2048 + tid * 8);
    floatx4 uu = *(const floatx4*)(ug + jt0 * 16 + lk * 4);
    __syncthreads();

    short8 rn;
    floatx4 uun;
    for (int t = 0; t < 32; ++t) {
        if (t < 31) {   // issue next-tile load early; lands during compute
            rn = *(const short8*)(kp + (size_t)(jt0 + t + 1) * 2048 + tid * 8);
            uun = *(const floatx4*)(ug + (jt0 + t + 1) * 16 + lk * 4);
        }
        short8 af[4];
#pragma unroll
        for (int ks = 0; ks < 4; ++ks)
            af[ks] = *(const short8*)(kls[t & 1] + (ks * 64 + lane) * 8);
        floatx4 sacc[2];
#pragma unroll
        for (int mt = 0; mt < 2; ++mt) sacc[mt] = (floatx4)0.0f;
#pragma unroll
        for (int ks = 0; ks < 4; ++ks)
#pragma unroll
            for (int mt = 0; mt < 2; ++mt)
                sacc[mt] = MFMA16(af[ks], qf[mt][ks], sacc[mt]);
#pragma unroll
        for (int mt = 0; mt < 2; ++mt) {
#pragma unroll
            for (int r = 0; r < 4; ++r) {
                float p = __builtin_amdgcn_exp2f(sacc[mt][r]);
                numv[mt] += p * uu[r];
                lsum[mt] += p;
            }
        }
        if (t < 31) {   // write-late: vmcnt drain lands after full compute phase
            *(short8*)(kls[(t + 1) & 1] + tid * 8) = rn;
            uu = uun;
        }
        __syncthreads();   // buf[t&1] reads done + buf[(t+1)&1] write visible
    }

    // reduce over lk (lane bits 4,5); store transposed packed partial (n,l)
#pragma unroll
    for (int mt = 0; mt < 2; ++mt) {
        float n = numv[mt], l = lsum[mt];
        n += __shfl_xor(n, 16); n += __shfl_xor(n, 32);
        l += __shfl_xor(l, 16); l += __shfl_xor(l, 32);
        if (lk == 0) {
            size_t row = (size_t)(rt0 + mt) * 16 + lr;
            pb[row * NSPLIT + blockIdx.y] = make_float2(n, l);
        }
    }
}

// ---------- K4: out[row] = (sum_s n_s) / (sum_s l_s) + b_out ----------
__global__ __launch_bounds__(256) void k_out(const float2* __restrict__ pb,
                                             const float* __restrict__ bout,
                                             float* __restrict__ out) {
    int row = blockIdx.x * 256 + threadIdx.x;
    const float2* p = pb + (size_t)row * NSPLIT;
    float n = 0.f, l = 0.f;
#pragma unroll
    for (int s = 0; s < NSPLIT; ++s) {
        float2 v = p[s];
        n += v.x; l += v.y;
    }
    out[row] = n / l + bout[0];
}

// ---------- launch ----------
extern "C" void kernel_launch(void* const* d_in, const int* in_sizes, int n_in,
                              void* d_out, int out_size, void* d_ws, size_t ws_size,
                              hipStream_t stream) {
    const float* x    = (const float*)d_in[0];
    const float* Wfc  = (const float*)d_in[1];
    const float* bfc  = (const float*)d_in[2];
    const float* Wg   = (const float*)d_in[3];
    const float* bg   = (const float*)d_in[4];
    const float* Wq   = (const float*)d_in[5];
    const float* bq   = (const float*)d_in[6];
    const float* Wk   = (const float*)d_in[7];
    const float* bk   = (const float*)d_in[8];
    const float* Wv   = (const float*)d_in[9];
    const float* bv   = (const float*)d_in[10];
    const float* Wout = (const float*)d_in[11];
    const float* bout = (const float*)d_in[12];
    char* ws = (char*)d_ws;

    unsigned short* qb   = (unsigned short*)(ws + Q_OFF);
    unsigned short* kb   = (unsigned short*)(ws + K_OFF);
    float*          ub   = (float*)(ws + U_OFF);
    unsigned short* wfcp = (unsigned short*)(ws + WFCT_OFF);
    unsigned short* wgp  = (unsigned short*)(ws + WGT_OFF);
    unsigned short* wqp  = (unsigned short*)(ws + WQT_OFF);
    unsigned short* wkp  = (unsigned short*)(ws + WKT_OFF);
    float*          wvo  = (float*)(ws + WVO_OFF);
    float2*         pbb  = (float2*)(ws + PB_OFF);

    k_prep<<<1217, 256, 0, stream>>>(Wfc, Wg, Wq, Wk, Wv, Wout, bv, wfcp, wgp, wqp, wkp, wvo);
    k_gq<<<256, 512, 0, stream>>>(x, wfcp, wgp, bfc, bg, wqp, wkp, bq, bk, wvo, qb, kb, ub);

    dim3 gf(64, NSPLIT);
    k_flash<<<gf, 256, 0, stream>>>(qb, kb, ub, pbb);

    k_out<<<32, 256, 0, stream>>>(pbb, bout, (float*)d_out);
}

// Round 5
// 136.356 us; speedup vs baseline: 1.8229x; 1.0134x over previous
//
#include <hip/hip_runtime.h>

// ---------- types ----------
typedef short short8 __attribute__((ext_vector_type(8)));        // 8 bf16 MFMA A/B frag
typedef float floatx4 __attribute__((ext_vector_type(4)));       // MFMA C/D frag

__device__ __forceinline__ unsigned short f2bf(float f) {
    unsigned u = __float_as_uint(f);
    u += 0x7fffu + ((u >> 16) & 1u);   // RNE
    return (unsigned short)(u >> 16);
}
__device__ __forceinline__ float bf2f(unsigned short b) {
    unsigned u = (unsigned)b << 16;
    return __uint_as_float(u);
}

#define MFMA16(a, b, c)  __builtin_amdgcn_mfma_f32_16x16x32_bf16((a), (b), (c), 0, 0, 0)

// ---------- ws layout (bytes) ----------
// Harness model (R4 post-mortem): dur_us = ~87us of 256MB ws re-poison fills
// (2 x 43.5us, constant) + our kernels (~47us at the r0 baseline). Optimize
// the kernels; judge by dur delta (fills constant).
// q/k PACKED in MFMA-fragment order: element (row, d) at
//   ((rowtile*4 + ks)*64 + lane)*8 + e ; one wave frag = one coalesced 1 KB txn.
static constexpr size_t Q_OFF    = 0;                    // q*QSCALE packed bf16 2 MB
static constexpr size_t K_OFF    = 2u << 20;             // k packed bf16        2 MB
static constexpr size_t U_OFF    = 4u << 20;             // u fp32 [8192]       32 KB
static constexpr size_t WFCT_OFF = U_OFF + 32768;        // W_fc packed bf16   256 KB
static constexpr size_t WGT_OFF  = WFCT_OFF + 262144;    // W_gate packed bf16
static constexpr size_t WQT_OFF  = WGT_OFF + 262144;     // W_q packed bf16     32 KB
static constexpr size_t WKT_OFF  = WQT_OFF + 32768;      // W_k packed bf16
static constexpr size_t WVO_OFF  = WKT_OFF + 32768;      // wvo fp32 [128] + c0
static constexpr size_t PB_OFF   = 5u << 20;             // partials float2 [8192][32] 2 MB

// R5: NSPLIT 16->32. v8 flash was GRID-limited to 2 waves/SIMD (2048 waves)
// while ~160 VGPR permits 3 (512/160). 1024 blocks -> 4096 waves -> 3/SIMD
// (+50% latency hiding) at CONSTANT total K-traffic (scales with x-blocks,
// not splits), shorter per-wave tail (16 iters), exact 4 blocks/CU.
static constexpr int NSPLIT = 32;
// log2(e)/sqrt(128): folded into stored q so P = exp2(S)
static constexpr float QSCALE = 0.1275174308f;

// ---------- K1: weights -> MFMA-packed bf16 + wvo = W_v @ W_out GEMV ----------
// Parallel GEMV (2 thr/output) — harness-verified in R4, kept (neutral+).
__global__ void k_prep(const float* __restrict__ wfc, const float* __restrict__ wg,
                       const float* __restrict__ wq, const float* __restrict__ wk,
                       const float* __restrict__ wv, const float* __restrict__ wout,
                       const float* __restrict__ bv,
                       unsigned short* __restrict__ dfc, unsigned short* __restrict__ dg,
                       unsigned short* __restrict__ dq, unsigned short* __restrict__ dk,
                       float* __restrict__ wvo) {
    if (blockIdx.x == 1216) {
        int t = threadIdx.x;
        {   // wvo[o] = dot(W_v[o,:], W_out): 2 threads per output
            int o = t >> 1, hf = t & 1;
            const float* wr = wv + o * 128 + hf * 64;
            const float* wo = wout + hf * 64;
            float s = 0.f;
#pragma unroll
            for (int j = 0; j < 64; ++j) s += wr[j] * wo[j];
            s += __shfl_xor(s, 1);
            if (hf == 0) wvo[o] = s;
        }
        if (t < 64) {   // c0 = bv @ W_out, one wave
            float s = bv[t] * wout[t] + bv[t + 64] * wout[t + 64];
#pragma unroll
            for (int d2 = 1; d2 < 64; d2 <<= 1) s += __shfl_xor(s, d2);
            if (t == 0) wvo[128] = s;
        }
        return;
    }
    int i = blockIdx.x * 256 + threadIdx.x;
    const float* s; unsigned short* d; int base, nchunk;
    if (i < 131072)      { s = wfc; d = dfc; nchunk = 32; base = 0; }
    else if (i < 262144) { s = wg;  d = dg;  nchunk = 32; base = 131072; }
    else if (i < 278528) { s = wq;  d = dq;  nchunk = 4;  base = 262144; }
    else if (i < 294912) { s = wk;  d = dk;  nchunk = 4;  base = 278528; }
    else return;
    int j = i - base;
    int kk = j >> 7, nn = j & 127;        // source W[kk][nn], row-major K x 128
    int t = nn >> 4, lr = nn & 15;
    int c = kk >> 5, lk = (kk >> 3) & 3, e = kk & 7;
    d[(((t * nchunk + c) * 64) + lr + 16 * lk) * 8 + e] = f2bf(s[j]);
}

// ---------- K2: fused gated-linear + QK + u (r12 structure, verbatim) ----------
__global__ __launch_bounds__(512) void k_gq(const float* __restrict__ x,
                                            const unsigned short* __restrict__ wfcp,
                                            const unsigned short* __restrict__ wgp,
                                            const float* __restrict__ bfc,
                                            const float* __restrict__ bg,
                                            const unsigned short* __restrict__ wqp,
                                            const unsigned short* __restrict__ wkp,
                                            const float* __restrict__ bq,
                                            const float* __restrict__ bk,
                                            const float* __restrict__ wvo,
                                            unsigned short* __restrict__ qpk,
                                            unsigned short* __restrict__ kpk,
                                            float* __restrict__ ug) {
    __shared__ __align__(16) unsigned short xs[2][32 * 136];
    __shared__ __align__(16) float gbuf[32 * 132];
    __shared__ __align__(16) unsigned short hs[32 * 136];
    const int tid = threadIdx.x;
    const int i0 = blockIdx.x * 32;
    const int w = tid >> 6, lane = tid & 63;
    const int lr = lane & 15, lk = lane >> 4;

    const int isg = (w >= 4);
    const int wq4 = w & 3;                 // 0..3: which 32-col group
    const unsigned short* wp = isg ? wgp : wfcp;

    floatx4 acc[2][2];
#pragma unroll
    for (int mt = 0; mt < 2; ++mt)
#pragma unroll
        for (int nt = 0; nt < 2; ++nt) acc[mt][nt] = (floatx4)0.0f;

    const int srow = tid >> 4, se = tid & 15;   // 32 rows x 16 thr, 8 floats each
    const float* gp0 = x + (size_t)(i0 + srow) * 1024 + se * 8;
    float4 ra = *(const float4*)gp0;
    float4 rb = *(const float4*)(gp0 + 4);

    for (int kc = 0; kc < 8; ++kc) {
        {   // commit prefetched chunk to LDS buf kc&1 (fp32 -> bf16)
            short8 t;
            unsigned short* tp = (unsigned short*)&t;
            tp[0] = f2bf(ra.x); tp[1] = f2bf(ra.y); tp[2] = f2bf(ra.z); tp[3] = f2bf(ra.w);
            tp[4] = f2bf(rb.x); tp[5] = f2bf(rb.y); tp[6] = f2bf(rb.z); tp[7] = f2bf(rb.w);
            *(short8*)(xs[kc & 1] + srow * 136 + se * 8) = t;
        }
        if (kc < 7) {
            const float* gp = gp0 + (kc + 1) * 128;
            ra = *(const float4*)gp;
            rb = *(const float4*)(gp + 4);
        }
        __syncthreads();
        const unsigned short* xb = xs[kc & 1];
#pragma unroll
        for (int ks = 0; ks < 4; ++ks) {
            const int c = kc * 4 + ks;
            short8 a[2], b[2];
#pragma unroll
            for (int mt = 0; mt < 2; ++mt)
                a[mt] = *(const short8*)(xb + (mt * 16 + lr) * 136 + ks * 32 + lk * 8);
#pragma unroll
            for (int nt = 0; nt < 2; ++nt)
                b[nt] = *(const short8*)(wp + ((((size_t)(wq4 * 2 + nt)) * 32 + c) * 64 + lane) * 8);
#pragma unroll
            for (int mt = 0; mt < 2; ++mt)
#pragma unroll
                for (int nt = 0; nt < 2; ++nt)
                    acc[mt][nt] = MFMA16(a[mt], b[nt], acc[mt][nt]);
        }
    }
    __syncthreads();
    // epilogue A: gate waves write sigmoid; fc waves combine -> h
    if (isg) {
#pragma unroll
        for (int mt = 0; mt < 2; ++mt)
#pragma unroll
            for (int nt = 0; nt < 2; ++nt) {
                int col = wq4 * 32 + nt * 16 + lr;
                float bb = bg[col];
#pragma unroll
                for (int r = 0; r < 4; ++r) {
                    float v = acc[mt][nt][r] + bb;
                    gbuf[(mt * 16 + lk * 4 + r) * 132 + col] =
                        __builtin_amdgcn_rcpf(1.0f + __builtin_amdgcn_exp2f(-1.4426950408889634f * v));
                }
            }
    }
    __syncthreads();
    if (!isg) {
#pragma unroll
        for (int mt = 0; mt < 2; ++mt)
#pragma unroll
            for (int nt = 0; nt < 2; ++nt) {
                int col = wq4 * 32 + nt * 16 + lr;
                float bb = bfc[col];
#pragma unroll
                for (int r = 0; r < 4; ++r) {
                    int row = mt * 16 + lk * 4 + r;
                    hs[row * 136 + col] = f2bf((acc[mt][nt][r] + bb) * gbuf[row * 132 + col]);
                }
            }
    }
    __syncthreads();

    // u[i] = h[i] @ wvo + c0 : thread t -> row t>>4, 8-elem chunk (t&15)*8
    {
        int row = tid >> 4, c = tid & 15;
        float s = 0.f;
#pragma unroll
        for (int e = 0; e < 8; ++e)
            s += bf2f(hs[row * 136 + c * 8 + e]) * wvo[c * 8 + e];
#pragma unroll
        for (int d = 1; d < 16; d <<= 1) s += __shfl_xor(s, d);
        if (c == 0) ug[i0 + row] = s + wvo[128];
    }

    // Phase B: q (w<4) | k (w>=4), 32 cols per wave, packed B
    floatx4 qacc[2][2];
#pragma unroll
    for (int mt = 0; mt < 2; ++mt)
#pragma unroll
        for (int nt = 0; nt < 2; ++nt) qacc[mt][nt] = (floatx4)0.0f;
    const unsigned short* wbp = (w < 4) ? wqp : wkp;
#pragma unroll
    for (int ks = 0; ks < 4; ++ks) {
        short8 a[2], b[2];
#pragma unroll
        for (int mt = 0; mt < 2; ++mt)
            a[mt] = *(const short8*)(hs + (mt * 16 + lr) * 136 + ks * 32 + lk * 8);
#pragma unroll
        for (int nt = 0; nt < 2; ++nt)
            b[nt] = *(const short8*)(wbp + ((((size_t)(wq4 * 2 + nt)) * 4 + ks) * 64 + lane) * 8);
#pragma unroll
        for (int mt = 0; mt < 2; ++mt)
#pragma unroll
            for (int nt = 0; nt < 2; ++nt)
                qacc[mt][nt] = MFMA16(a[mt], b[nt], qacc[mt][nt]);
    }
    // epilogue B: bias+scale -> LDS tile (xs reused: [0]=q, [1]=k)
    {
        unsigned short* dstl = xs[isg];
        const float* bb_ = (w < 4) ? bq : bk;
        const float sc = (w < 4) ? QSCALE : 1.0f;
#pragma unroll
        for (int mt = 0; mt < 2; ++mt)
#pragma unroll
            for (int nt = 0; nt < 2; ++nt) {
                int col = wq4 * 32 + nt * 16 + lr;
                float bb = bb_[col];
#pragma unroll
                for (int r = 0; r < 4; ++r)
                    dstl[(mt * 16 + lk * 4 + r) * 136 + col] = f2bf((qacc[mt][nt][r] + bb) * sc);
            }
    }
    __syncthreads();
    // cooperative packed store: 16 segments (sel,rtl,ks), wave w -> sel=w>>2, 2 ks each
    {
        int sel = w >> 2, p = w & 3;
        int rtl = p >> 1, ks2 = (p & 1) * 2;
        unsigned short* gdst = sel ? kpk : qpk;
        const unsigned short* src = xs[sel];
        size_t rt = (i0 >> 4) + rtl;
#pragma unroll
        for (int s = 0; s < 2; ++s) {
            int ks = ks2 + s;
            short8 v = *(const short8*)(src + (rtl * 16 + lr) * 136 + ks * 32 + lk * 8);
            *(short8*)(gdst + ((rt * 4 + ks) * 64 + lane) * 8) = v;
        }
    }
}

// ---------- K3: flash v10 — v8 structure (barrier-free, reg prefetch), NSPLIT 32 ----------
// R4 evidence: v9 (LDS-staged, barrier/iter) regressed +4us -> NOT L2-BW-bound;
// latency/TLP-bound (r2: MfmaUtil 6.4, VALUBusy 9.7, Occ 22). v8 was
// grid-limited to 2 waves/SIMD; VGPR (~160) allows 3. NSPLIT=32: grid (32,32)
// = 4096 waves -> 3/SIMD, same total K traffic, 16-iter tail, 4 blocks/CU.
// Math identical per wave (same MFMA/exp2/acc order); only split size changes.
// launch_bounds(256,1): do NOT cap VGPR below ~160 (r6: spill storm).
__global__ __launch_bounds__(256, 1) void k_flash(const unsigned short* __restrict__ qp,
                                                  const unsigned short* __restrict__ kp,
                                                  const float* __restrict__ ug,
                                                  float2* __restrict__ pb) {
    const int tid = threadIdx.x;
    const int w = tid >> 6, lane = tid & 63;
    const int lr = lane & 15, lk = lane >> 4;
    const int rt0 = blockIdx.x * 16 + w * 4;    // q row-tile base

    // Q frags: 16 coalesced 1KB loads, live in registers
    short8 qf[4][4];
#pragma unroll
    for (int mt = 0; mt < 4; ++mt)
#pragma unroll
        for (int ks = 0; ks < 4; ++ks)
            qf[mt][ks] = *(const short8*)(qp + (((size_t)(rt0 + mt) * 4 + ks) * 64 + lane) * 8);

    float numv[4] = {0.f, 0.f, 0.f, 0.f};
    float lsum[4] = {0.f, 0.f, 0.f, 0.f};

    const int jt0 = blockIdx.y * 16;            // 16 j row-tiles per split (NSPLIT=32)

    short8 af[4], afn[4];
    floatx4 uu, uun;
#pragma unroll
    for (int ks = 0; ks < 4; ++ks)
        af[ks] = *(const short8*)(kp + (((size_t)jt0 * 4 + ks) * 64 + lane) * 8);
    uu = *(const floatx4*)(ug + jt0 * 16 + lk * 4);

    for (int t = 0; t < 16; ++t) {
        if (t < 15) {   // prefetch next sub-tile (stays in flight across the MFMAs)
#pragma unroll
            for (int ks = 0; ks < 4; ++ks)
                afn[ks] = *(const short8*)(kp + (((size_t)(jt0 + t + 1) * 4 + ks) * 64 + lane) * 8);
            uun = *(const floatx4*)(ug + (jt0 + t + 1) * 16 + lk * 4);
        }
        floatx4 sacc[4];
#pragma unroll
        for (int mt = 0; mt < 4; ++mt) sacc[mt] = (floatx4)0.0f;
#pragma unroll
        for (int ks = 0; ks < 4; ++ks)
#pragma unroll
            for (int mt = 0; mt < 4; ++mt)
                sacc[mt] = MFMA16(af[ks], qf[mt][ks], sacc[mt]);
#pragma unroll
        for (int mt = 0; mt < 4; ++mt) {
#pragma unroll
            for (int r = 0; r < 4; ++r) {
                float p = __builtin_amdgcn_exp2f(sacc[mt][r]);
                numv[mt] += p * uu[r];
                lsum[mt] += p;
            }
        }
#pragma unroll
        for (int ks = 0; ks < 4; ++ks) af[ks] = afn[ks];
        uu = uun;
    }

    // reduce over lk (lane bits 4,5); store transposed packed partial (n,l)
#pragma unroll
    for (int mt = 0; mt < 4; ++mt) {
        float n = numv[mt], l = lsum[mt];
        n += __shfl_xor(n, 16); n += __shfl_xor(n, 32);
        l += __shfl_xor(l, 16); l += __shfl_xor(l, 32);
        if (lk == 0) {
            size_t row = (size_t)(rt0 + mt) * 16 + lr;
            pb[row * NSPLIT + blockIdx.y] = make_float2(n, l);
        }
    }
}

// ---------- K4: out[row] = (sum_s n_s) / (sum_s l_s) + b_out ----------
// one thread per row; 256 B coalesced read of the row's 32 float2 partials.
__global__ __launch_bounds__(256) void k_out(const float2* __restrict__ pb,
                                             const float* __restrict__ bout,
                                             float* __restrict__ out) {
    int row = blockIdx.x * 256 + threadIdx.x;
    const float2* p = pb + (size_t)row * NSPLIT;
    float n = 0.f, l = 0.f;
#pragma unroll
    for (int s = 0; s < NSPLIT; ++s) {
        float2 v = p[s];
        n += v.x; l += v.y;
    }
    out[row] = n / l + bout[0];
}

// ---------- launch ----------
extern "C" void kernel_launch(void* const* d_in, const int* in_sizes, int n_in,
                              void* d_out, int out_size, void* d_ws, size_t ws_size,
                              hipStream_t stream) {
    const float* x    = (const float*)d_in[0];
    const float* Wfc  = (const float*)d_in[1];
    const float* bfc  = (const float*)d_in[2];
    const float* Wg   = (const float*)d_in[3];
    const float* bg   = (const float*)d_in[4];
    const float* Wq   = (const float*)d_in[5];
    const float* bq   = (const float*)d_in[6];
    const float* Wk   = (const float*)d_in[7];
    const float* bk   = (const float*)d_in[8];
    const float* Wv   = (const float*)d_in[9];
    const float* bv   = (const float*)d_in[10];
    const float* Wout = (const float*)d_in[11];
    const float* bout = (const float*)d_in[12];
    char* ws = (char*)d_ws;

    unsigned short* qb   = (unsigned short*)(ws + Q_OFF);
    unsigned short* kb   = (unsigned short*)(ws + K_OFF);
    float*          ub   = (float*)(ws + U_OFF);
    unsigned short* wfcp = (unsigned short*)(ws + WFCT_OFF);
    unsigned short* wgp  = (unsigned short*)(ws + WGT_OFF);
    unsigned short* wqp  = (unsigned short*)(ws + WQT_OFF);
    unsigned short* wkp  = (unsigned short*)(ws + WKT_OFF);
    float*          wvo  = (float*)(ws + WVO_OFF);
    float2*         pbb  = (float2*)(ws + PB_OFF);

    k_prep<<<1217, 256, 0, stream>>>(Wfc, Wg, Wq, Wk, Wv, Wout, bv, wfcp, wgp, wqp, wkp, wvo);
    k_gq<<<256, 512, 0, stream>>>(x, wfcp, wgp, bfc, bg, wqp, wkp, bq, bk, wvo, qb, kb, ub);

    dim3 gf(32, NSPLIT);
    k_flash<<<gf, 256, 0, stream>>>(qb, kb, ub, pbb);

    k_out<<<32, 256, 0, stream>>>(pbb, bout, (float*)d_out);
}

// Round 6
// 128.402 us; speedup vs baseline: 1.9358x; 1.0619x over previous
//
#include <hip/hip_runtime.h>

// ---------- types ----------
typedef short short8 __attribute__((ext_vector_type(8)));        // 8 bf16 MFMA A/B frag
typedef float floatx4 __attribute__((ext_vector_type(4)));       // MFMA C/D frag

__device__ __forceinline__ unsigned short f2bf(float f) {
    unsigned u = __float_as_uint(f);
    u += 0x7fffu + ((u >> 16) & 1u);   // RNE
    return (unsigned short)(u >> 16);
}
__device__ __forceinline__ float bf2f(unsigned short b) {
    unsigned u = (unsigned)b << 16;
    return __uint_as_float(u);
}

#define MFMA16(a, b, c)  __builtin_amdgcn_mfma_f32_16x16x32_bf16((a), (b), (c), 0, 0, 0)

// ---------- ws layout (bytes) ----------
// R5 ledger: r0 (this structure) = 134.3us best. Fused coop = wash (drains not
// the cost). v9 LDS-staged flash = +4 (not L2-BW-bound). NSPLIT32 3waves/SIMD
// = +2 (not TLP-bound). => residual is per-wave EXPOSED LOAD LATENCY.
// R6 changes: flash 2-deep prefetch + setprio(MFMA); gq kc-unroll + B-frag
// register prefetch. All else exact r0.
static constexpr size_t Q_OFF    = 0;                    // q*QSCALE packed bf16 2 MB
static constexpr size_t K_OFF    = 2u << 20;             // k packed bf16        2 MB
static constexpr size_t U_OFF    = 4u << 20;             // u fp32 [8192]       32 KB
static constexpr size_t WFCT_OFF = U_OFF + 32768;        // W_fc packed bf16   256 KB
static constexpr size_t WGT_OFF  = WFCT_OFF + 262144;    // W_gate packed bf16
static constexpr size_t WQT_OFF  = WGT_OFF + 262144;     // W_q packed bf16     32 KB
static constexpr size_t WKT_OFF  = WQT_OFF + 32768;      // W_k packed bf16
static constexpr size_t WVO_OFF  = WKT_OFF + 32768;      // wvo fp32 [128] + c0
static constexpr size_t PB_OFF   = 5u << 20;             // partials float2 [8192][16] 1 MB

static constexpr int NSPLIT = 16;
// log2(e)/sqrt(128): folded into stored q so P = exp2(S)
static constexpr float QSCALE = 0.1275174308f;

// ---------- K1: weights -> MFMA-packed bf16 + wvo = W_v @ W_out GEMV (r0 exact) ----------
__global__ void k_prep(const float* __restrict__ wfc, const float* __restrict__ wg,
                       const float* __restrict__ wq, const float* __restrict__ wk,
                       const float* __restrict__ wv, const float* __restrict__ wout,
                       const float* __restrict__ bv,
                       unsigned short* __restrict__ dfc, unsigned short* __restrict__ dg,
                       unsigned short* __restrict__ dq, unsigned short* __restrict__ dk,
                       float* __restrict__ wvo) {
    if (blockIdx.x == 1216) {
        int t = threadIdx.x;
        if (t < 128) {
            float s = 0.f;
            for (int j = 0; j < 128; ++j) s += wv[t * 128 + j] * wout[j];
            wvo[t] = s;
        } else if (t == 128) {
            float s = 0.f;
            for (int j = 0; j < 128; ++j) s += bv[j] * wout[j];
            wvo[128] = s;   // c0
        }
        return;
    }
    int i = blockIdx.x * 256 + threadIdx.x;
    const float* s; unsigned short* d; int base, nchunk;
    if (i < 131072)      { s = wfc; d = dfc; nchunk = 32; base = 0; }
    else if (i < 262144) { s = wg;  d = dg;  nchunk = 32; base = 131072; }
    else if (i < 278528) { s = wq;  d = dq;  nchunk = 4;  base = 262144; }
    else if (i < 294912) { s = wk;  d = dk;  nchunk = 4;  base = 278528; }
    else return;
    int j = i - base;
    int kk = j >> 7, nn = j & 127;        // source W[kk][nn], row-major K x 128
    int t = nn >> 4, lr = nn & 15;
    int c = kk >> 5, lk = (kk >> 3) & 3, e = kk & 7;
    d[(((t * nchunk + c) * 64) + lr + 16 * lk) * 8 + e] = f2bf(s[j]);
}

// ---------- K2: fused gated-linear + QK + u ----------
// R6: kc-loop #pragma unroll + B-frags register-prefetched one kc ahead,
// issued FIRST after the barrier -> each weight load gets a full MFMA-phase
// (~150-200cyc) window instead of ~0 (was loaded right before use).
__global__ __launch_bounds__(512) void k_gq(const float* __restrict__ x,
                                            const unsigned short* __restrict__ wfcp,
                                            const unsigned short* __restrict__ wgp,
                                            const float* __restrict__ bfc,
                                            const float* __restrict__ bg,
                                            const unsigned short* __restrict__ wqp,
                                            const unsigned short* __restrict__ wkp,
                                            const float* __restrict__ bq,
                                            const float* __restrict__ bk,
                                            const float* __restrict__ wvo,
                                            unsigned short* __restrict__ qpk,
                                            unsigned short* __restrict__ kpk,
                                            float* __restrict__ ug) {
    __shared__ __align__(16) unsigned short xs[2][32 * 136];
    __shared__ __align__(16) float gbuf[32 * 132];
    __shared__ __align__(16) unsigned short hs[32 * 136];
    const int tid = threadIdx.x;
    const int i0 = blockIdx.x * 32;
    const int w = tid >> 6, lane = tid & 63;
    const int lr = lane & 15, lk = lane >> 4;

    const int isg = (w >= 4);
    const int wq4 = w & 3;                 // 0..3: which 32-col group
    const unsigned short* wp = isg ? wgp : wfcp;

    floatx4 acc[2][2];
#pragma unroll
    for (int mt = 0; mt < 2; ++mt)
#pragma unroll
        for (int nt = 0; nt < 2; ++nt) acc[mt][nt] = (floatx4)0.0f;

    const int srow = tid >> 4, se = tid & 15;   // 32 rows x 16 thr, 8 floats each
    const float* gp0 = x + (size_t)(i0 + srow) * 1024 + se * 8;
    float4 ra = *(const float4*)gp0;
    float4 rb = *(const float4*)(gp0 + 4);

    // bfr[kc&1][ks][nt]: current/next kc weight frags (64 VGPR), preload kc=0
    short8 bfr[2][4][2];
#pragma unroll
    for (int ks = 0; ks < 4; ++ks)
#pragma unroll
        for (int nt = 0; nt < 2; ++nt)
            bfr[0][ks][nt] = *(const short8*)(wp + ((((size_t)(wq4 * 2 + nt)) * 32 + ks) * 64 + lane) * 8);

#pragma unroll
    for (int kc = 0; kc < 8; ++kc) {
        {   // commit prefetched chunk to LDS buf kc&1 (fp32 -> bf16)
            short8 t;
            unsigned short* tp = (unsigned short*)&t;
            tp[0] = f2bf(ra.x); tp[1] = f2bf(ra.y); tp[2] = f2bf(ra.z); tp[3] = f2bf(ra.w);
            tp[4] = f2bf(rb.x); tp[5] = f2bf(rb.y); tp[6] = f2bf(rb.z); tp[7] = f2bf(rb.w);
            *(short8*)(xs[kc & 1] + srow * 136 + se * 8) = t;
        }
        if (kc < 7) {
            const float* gp = gp0 + (kc + 1) * 128;
            ra = *(const float4*)gp;
            rb = *(const float4*)(gp + 4);
        }
        __syncthreads();
        if (kc < 7) {   // issue next-kc weight loads; land during this kc's MFMAs
#pragma unroll
            for (int ks = 0; ks < 4; ++ks)
#pragma unroll
                for (int nt = 0; nt < 2; ++nt)
                    bfr[(kc + 1) & 1][ks][nt] =
                        *(const short8*)(wp + ((((size_t)(wq4 * 2 + nt)) * 32 + ((kc + 1) * 4 + ks)) * 64 + lane) * 8);
        }
        const unsigned short* xb = xs[kc & 1];
#pragma unroll
        for (int ks = 0; ks < 4; ++ks) {
            short8 a[2];
#pragma unroll
            for (int mt = 0; mt < 2; ++mt)
                a[mt] = *(const short8*)(xb + (mt * 16 + lr) * 136 + ks * 32 + lk * 8);
#pragma unroll
            for (int mt = 0; mt < 2; ++mt)
#pragma unroll
                for (int nt = 0; nt < 2; ++nt)
                    acc[mt][nt] = MFMA16(a[mt], bfr[kc & 1][ks][nt], acc[mt][nt]);
        }
    }
    __syncthreads();
    // epilogue A: gate waves write sigmoid; fc waves combine -> h
    if (isg) {
#pragma unroll
        for (int mt = 0; mt < 2; ++mt)
#pragma unroll
            for (int nt = 0; nt < 2; ++nt) {
                int col = wq4 * 32 + nt * 16 + lr;
                float bb = bg[col];
#pragma unroll
                for (int r = 0; r < 4; ++r) {
                    float v = acc[mt][nt][r] + bb;
                    gbuf[(mt * 16 + lk * 4 + r) * 132 + col] =
                        __builtin_amdgcn_rcpf(1.0f + __builtin_amdgcn_exp2f(-1.4426950408889634f * v));
                }
            }
    }
    __syncthreads();
    if (!isg) {
#pragma unroll
        for (int mt = 0; mt < 2; ++mt)
#pragma unroll
            for (int nt = 0; nt < 2; ++nt) {
                int col = wq4 * 32 + nt * 16 + lr;
                float bb = bfc[col];
#pragma unroll
                for (int r = 0; r < 4; ++r) {
                    int row = mt * 16 + lk * 4 + r;
                    hs[row * 136 + col] = f2bf((acc[mt][nt][r] + bb) * gbuf[row * 132 + col]);
                }
            }
    }
    __syncthreads();

    // u[i] = h[i] @ wvo + c0 : thread t -> row t>>4, 8-elem chunk (t&15)*8
    {
        int row = tid >> 4, c = tid & 15;
        float s = 0.f;
#pragma unroll
        for (int e = 0; e < 8; ++e)
            s += bf2f(hs[row * 136 + c * 8 + e]) * wvo[c * 8 + e];
#pragma unroll
        for (int d = 1; d < 16; d <<= 1) s += __shfl_xor(s, d);
        if (c == 0) ug[i0 + row] = s + wvo[128];
    }

    // Phase B: q (w<4) | k (w>=4), 32 cols per wave, packed B
    floatx4 qacc[2][2];
#pragma unroll
    for (int mt = 0; mt < 2; ++mt)
#pragma unroll
        for (int nt = 0; nt < 2; ++nt) qacc[mt][nt] = (floatx4)0.0f;
    const unsigned short* wbp = (w < 4) ? wqp : wkp;
#pragma unroll
    for (int ks = 0; ks < 4; ++ks) {
        short8 a[2], b[2];
#pragma unroll
        for (int mt = 0; mt < 2; ++mt)
            a[mt] = *(const short8*)(hs + (mt * 16 + lr) * 136 + ks * 32 + lk * 8);
#pragma unroll
        for (int nt = 0; nt < 2; ++nt)
            b[nt] = *(const short8*)(wbp + ((((size_t)(wq4 * 2 + nt)) * 4 + ks) * 64 + lane) * 8);
#pragma unroll
        for (int mt = 0; mt < 2; ++mt)
#pragma unroll
            for (int nt = 0; nt < 2; ++nt)
                qacc[mt][nt] = MFMA16(a[mt], b[nt], qacc[mt][nt]);
    }
    // epilogue B: bias+scale -> LDS tile (xs reused: [0]=q, [1]=k)
    {
        unsigned short* dstl = xs[isg];
        const float* bb_ = (w < 4) ? bq : bk;
        const float sc = (w < 4) ? QSCALE : 1.0f;
#pragma unroll
        for (int mt = 0; mt < 2; ++mt)
#pragma unroll
            for (int nt = 0; nt < 2; ++nt) {
                int col = wq4 * 32 + nt * 16 + lr;
                float bb = bb_[col];
#pragma unroll
                for (int r = 0; r < 4; ++r)
                    dstl[(mt * 16 + lk * 4 + r) * 136 + col] = f2bf((qacc[mt][nt][r] + bb) * sc);
            }
    }
    __syncthreads();
    // cooperative packed store: 16 segments (sel,rtl,ks), wave w -> sel=w>>2, 2 ks each
    {
        int sel = w >> 2, p = w & 3;
        int rtl = p >> 1, ks2 = (p & 1) * 2;
        unsigned short* gdst = sel ? kpk : qpk;
        const unsigned short* src = xs[sel];
        size_t rt = (i0 >> 4) + rtl;
#pragma unroll
        for (int s = 0; s < 2; ++s) {
            int ks = ks2 + s;
            short8 v = *(const short8*)(src + (rtl * 16 + lr) * 136 + ks * 32 + lk * 8);
            *(short8*)(gdst + ((rt * 4 + ks) * 64 + lane) * 8) = v;
        }
    }
}

// ---------- K3: flash v12 — v8 structure + 2-deep prefetch + setprio ----------
// R6: ping-pong af0/af1 (2 sub-tiles in flight; window 1.5-2 sub-tiles
// ~300-500cyc covers L2-under-load latency; v8's 1-deep = ~130-250cyc
// partially exposed). setprio(1) around MFMA cluster: T5 positive for
// barrier-free independent attn waves (m191); flash is exactly that.
// Accumulation order identical to v8 (ascending t) -> same absmax.
// launch_bounds(256,1): ~160 VGPR — do NOT cap below (r6: spill storm).
__global__ __launch_bounds__(256, 1) void k_flash(const unsigned short* __restrict__ qp,
                                                  const unsigned short* __restrict__ kp,
                                                  const float* __restrict__ ug,
                                                  float2* __restrict__ pb) {
    const int tid = threadIdx.x;
    const int w = tid >> 6, lane = tid & 63;
    const int lr = lane & 15, lk = lane >> 4;
    const int rt0 = blockIdx.x * 16 + w * 4;    // q row-tile base

    // Q frags: 16 coalesced 1KB loads, live in registers
    short8 qf[4][4];
#pragma unroll
    for (int mt = 0; mt < 4; ++mt)
#pragma unroll
        for (int ks = 0; ks < 4; ++ks)
            qf[mt][ks] = *(const short8*)(qp + (((size_t)(rt0 + mt) * 4 + ks) * 64 + lane) * 8);

    float numv[4] = {0.f, 0.f, 0.f, 0.f};
    float lsum[4] = {0.f, 0.f, 0.f, 0.f};

    const int jt0 = blockIdx.y * 32;            // 32 j sub-tiles per split

    short8 af0[4], af1[4];
    floatx4 uu0, uu1;
#pragma unroll
    for (int ks = 0; ks < 4; ++ks) {
        af0[ks] = *(const short8*)(kp + (((size_t)(jt0 + 0) * 4 + ks) * 64 + lane) * 8);
        af1[ks] = *(const short8*)(kp + (((size_t)(jt0 + 1) * 4 + ks) * 64 + lane) * 8);
    }
    uu0 = *(const floatx4*)(ug + (jt0 + 0) * 16 + lk * 4);
    uu1 = *(const floatx4*)(ug + (jt0 + 1) * 16 + lk * 4);

    for (int tt = 0; tt < 16; ++tt) {
        const int tb = jt0 + tt * 2;
        // ---- even sub-tile (af0) ----
        {
            floatx4 sacc[4];
#pragma unroll
            for (int mt = 0; mt < 4; ++mt) sacc[mt] = (floatx4)0.0f;
            __builtin_amdgcn_s_setprio(1);
#pragma unroll
            for (int ks = 0; ks < 4; ++ks)
#pragma unroll
                for (int mt = 0; mt < 4; ++mt)
                    sacc[mt] = MFMA16(af0[ks], qf[mt][ks], sacc[mt]);
            __builtin_amdgcn_s_setprio(0);
            if (tt < 15) {   // refill af0 for t+2: in flight across odd sub-tile
#pragma unroll
                for (int ks = 0; ks < 4; ++ks)
                    af0[ks] = *(const short8*)(kp + (((size_t)(tb + 2) * 4 + ks) * 64 + lane) * 8);
            }
#pragma unroll
            for (int mt = 0; mt < 4; ++mt)
#pragma unroll
                for (int r = 0; r < 4; ++r) {
                    float p = __builtin_amdgcn_exp2f(sacc[mt][r]);
                    numv[mt] += p * uu0[r];
                    lsum[mt] += p;
                }
            if (tt < 15) uu0 = *(const floatx4*)(ug + (tb + 2) * 16 + lk * 4);
        }
        // ---- odd sub-tile (af1) ----
        {
            floatx4 sacc[4];
#pragma unroll
            for (int mt = 0; mt < 4; ++mt) sacc[mt] = (floatx4)0.0f;
            __builtin_amdgcn_s_setprio(1);
#pragma unroll
            for (int ks = 0; ks < 4; ++ks)
#pragma unroll
                for (int mt = 0; mt < 4; ++mt)
                    sacc[mt] = MFMA16(af1[ks], qf[mt][ks], sacc[mt]);
            __builtin_amdgcn_s_setprio(0);
            if (tt < 15) {   // refill af1 for t+3: in flight across next even sub-tile
#pragma unroll
                for (int ks = 0; ks < 4; ++ks)
                    af1[ks] = *(const short8*)(kp + (((size_t)(tb + 3) * 4 + ks) * 64 + lane) * 8);
            }
#pragma unroll
            for (int mt = 0; mt < 4; ++mt)
#pragma unroll
                for (int r = 0; r < 4; ++r) {
                    float p = __builtin_amdgcn_exp2f(sacc[mt][r]);
                    numv[mt] += p * uu1[r];
                    lsum[mt] += p;
                }
            if (tt < 15) uu1 = *(const floatx4*)(ug + (tb + 3) * 16 + lk * 4);
        }
    }

    // reduce over lk (lane bits 4,5); store transposed packed partial (n,l)
#pragma unroll
    for (int mt = 0; mt < 4; ++mt) {
        float n = numv[mt], l = lsum[mt];
        n += __shfl_xor(n, 16); n += __shfl_xor(n, 32);
        l += __shfl_xor(l, 16); l += __shfl_xor(l, 32);
        if (lk == 0) {
            size_t row = (size_t)(rt0 + mt) * 16 + lr;
            pb[row * NSPLIT + blockIdx.y] = make_float2(n, l);
        }
    }
}

// ---------- K4: out[row] = (sum_s n_s) / (sum_s l_s) + b_out (r0 exact) ----------
__global__ __launch_bounds__(256) void k_out(const float2* __restrict__ pb,
                                             const float* __restrict__ bout,
                                             float* __restrict__ out) {
    int row = blockIdx.x * 256 + threadIdx.x;
    const float2* p = pb + (size_t)row * NSPLIT;
    float n = 0.f, l = 0.f;
#pragma unroll
    for (int s = 0; s < NSPLIT; ++s) {
        float2 v = p[s];
        n += v.x; l += v.y;
    }
    out[row] = n / l + bout[0];
}

// ---------- launch ----------
extern "C" void kernel_launch(void* const* d_in, const int* in_sizes, int n_in,
                              void* d_out, int out_size, void* d_ws, size_t ws_size,
                              hipStream_t stream) {
    const float* x    = (const float*)d_in[0];
    const float* Wfc  = (const float*)d_in[1];
    const float* bfc  = (const float*)d_in[2];
    const float* Wg   = (const float*)d_in[3];
    const float* bg   = (const float*)d_in[4];
    const float* Wq   = (const float*)d_in[5];
    const float* bq   = (const float*)d_in[6];
    const float* Wk   = (const float*)d_in[7];
    const float* bk   = (const float*)d_in[8];
    const float* Wv   = (const float*)d_in[9];
    const float* bv   = (const float*)d_in[10];
    const float* Wout = (const float*)d_in[11];
    const float* bout = (const float*)d_in[12];
    char* ws = (char*)d_ws;

    unsigned short* qb   = (unsigned short*)(ws + Q_OFF);
    unsigned short* kb   = (unsigned short*)(ws + K_OFF);
    float*          ub   = (float*)(ws + U_OFF);
    unsigned short* wfcp = (unsigned short*)(ws + WFCT_OFF);
    unsigned short* wgp  = (unsigned short*)(ws + WGT_OFF);
    unsigned short* wqp  = (unsigned short*)(ws + WQT_OFF);
    unsigned short* wkp  = (unsigned short*)(ws + WKT_OFF);
    float*          wvo  = (float*)(ws + WVO_OFF);
    float2*         pbb  = (float2*)(ws + PB_OFF);

    k_prep<<<1217, 256, 0, stream>>>(Wfc, Wg, Wq, Wk, Wv, Wout, bv, wfcp, wgp, wqp, wkp, wvo);
    k_gq<<<256, 512, 0, stream>>>(x, wfcp, wgp, bfc, bg, wqp, wkp, bq, bk, wvo, qb, kb, ub);

    dim3 gf(32, NSPLIT);
    k_flash<<<gf, 256, 0, stream>>>(qb, kb, ub, pbb);

    k_out<<<32, 256, 0, stream>>>(pbb, bout, (float*)d_out);
}